// Round 3
// baseline (215.926 us; speedup 1.0000x reference)
//
#include <hip/hip_runtime.h>

// Scatter-permute: out[expert_offsets[expert_idx[t]] + slot_idx[t], :] = token_hidden[t, :]
// T=65536 tokens, D=2048 f32 (8 KB/row). rows form a bijection over [0,T) ->
// every output row is written exactly once, so no zero-init of d_out is needed.
//
// Memory-bound: 1.074 GB total traffic; seq-copy ceiling ~6.3 TB/s -> ~171 us.
// R1 (block/row, 2x f32x4/lane, plain):        206 us = 5.2 TB/s
// R2 (grid-stride + nontemporal ld/st):        212 us  (NT loads + loop serial-
//                                               ization regressed; reverted)
// R3: one WAVE per row, 8x f32x4 per lane, loads batched before stores ->
//     4x deeper vmem pipelining per lane and coarser same-direction bursts
//     (fewer read<->write turnarounds), plain temporal ld/st.

typedef float f32x4 __attribute__((ext_vector_type(4)));

__global__ void __launch_bounds__(256)
scatter_rows_kernel(const f32x4* __restrict__ src,
                    const int* __restrict__ expert_idx,
                    const int* __restrict__ slot_idx,
                    const int* __restrict__ expert_offsets,
                    f32x4* __restrict__ dst)
{
    // One wave (64 lanes) per row; 4 rows per 256-thread block.
    // Row = blockIdx.x*4 + wave_id; lane copies 8 f32x4 at stride 64.
    const int lane = threadIdx.x & 63;
    const int wid  = threadIdx.x >> 6;
    const int t    = blockIdx.x * 4 + wid;

    // Force the index chain scalar (wave-uniform t).
    const int ts   = __builtin_amdgcn_readfirstlane(t);
    const int e    = __builtin_amdgcn_readfirstlane(expert_idx[ts]);
    const int row  = __builtin_amdgcn_readfirstlane(expert_offsets[e] + slot_idx[ts]);

    const f32x4* s = src + (size_t)ts  * 512 + lane;
    f32x4*       d = dst + (size_t)row * 512 + lane;

    f32x4 v[8];
#pragma unroll
    for (int j = 0; j < 8; ++j) v[j] = s[j * 64];
#pragma unroll
    for (int j = 0; j < 8; ++j) d[j * 64] = v[j];
}

extern "C" void kernel_launch(void* const* d_in, const int* in_sizes, int n_in,
                              void* d_out, int out_size, void* d_ws, size_t ws_size,
                              hipStream_t stream) {
    const float* token_hidden   = (const float*)d_in[0];
    const int*   expert_idx     = (const int*)  d_in[1];
    const int*   slot_idx       = (const int*)  d_in[2];
    const int*   expert_offsets = (const int*)  d_in[3];

    const int T = in_sizes[1];            // 65536 tokens (rows)

    scatter_rows_kernel<<<T / 4, 256, 0, stream>>>(
        (const f32x4*)token_hidden, expert_idx, slot_idx, expert_offsets,
        (f32x4*)d_out);
}